// Round 15
// baseline (1422.431 us; speedup 1.0000x reference)
//
#include <hip/hip_runtime.h>
#include <hip/hip_bf16.h>

#define N_NODES 50000
#define N_EDGES 600000
#define DD 128
#define N_LAYERS 6
#define SCAN_BLOCKS 196   // ceil(50000/256)
#define N_CHUNKS 3125     // 50000 / 16 exactly
#define N_HC 6250         // half-chunks (8 nodes each)
#define AGG_BLOCKS 6256

#define XB16_T 1600000    // x_to_bf16 threads: N_NODES*DD/4 elements-of-4
#define ZERO_T 50112      // 50000 deg/cursor + 112 dispenser ints
#define PREPW_T 196608
#define PREP_TOTAL (XB16_T + ZERO_T + PREPW_T)

#define XCC_IMM 63508     // hwreg(HW_REG_XCC_ID=20, offset 0, size 32)

typedef __attribute__((ext_vector_type(8))) short bf16x8;
typedef __attribute__((ext_vector_type(4))) float floatx4;

__device__ __forceinline__ void ldsdma16(const void* g, void* l) {
    __builtin_amdgcn_global_load_lds(
        (const __attribute__((address_space(1))) char*)g,
        (__attribute__((address_space(3))) char*)l, 16, 0, 0);
}

__device__ __forceinline__ unsigned short f2b(float f) {
    unsigned u = __float_as_uint(f);
    unsigned r = (u + 0x7FFFu + ((u >> 16) & 1u)) >> 16;
    return (unsigned short)r;
}

// ---------------- merged prep: x->bf16, zero counters+dispensers, weights transpose ----------------

__global__ void prep_all(const float* __restrict__ x, unsigned short* __restrict__ hx,
                         const float* __restrict__ Wl, const float* __restrict__ Wr,
                         unsigned short* __restrict__ WT2,
                         int* __restrict__ deg, int* __restrict__ cursor,
                         int* __restrict__ disp) {
    int gid = blockIdx.x * blockDim.x + threadIdx.x;
    if (gid < XB16_T) {
        int b = gid * 4;
        float4 v = *(const float4*)(x + b);
        ushort4 o;
        o.x = f2b(v.x); o.y = f2b(v.y); o.z = f2b(v.z); o.w = f2b(v.w);
        *(ushort4*)(hx + b) = o;
    } else if (gid < XB16_T + ZERO_T) {
        int i = gid - XB16_T;
        if (i < 50000) { deg[i] = 0; cursor[i] = 0; }
        else disp[i - 50000] = 0;     // 112 dispenser slots (96 used)
    } else if (gid < PREP_TOTAL) {
        int idx = gid - (XB16_T + ZERO_T);
        int l   = idx >> 15;
        int rem = idx & 32767;
        int n   = rem >> 8;
        int k2  = rem & 255;
        const float* W = (k2 < 128 ? Wl : Wr) + (size_t)l * DD * DD + (size_t)(k2 & 127) * DD + n;
        WT2[idx] = f2b(*W);
    }
}

// ---------------- CSR build ----------------

__global__ void count_deg(const int* __restrict__ dst, int* __restrict__ deg) {
    int e = blockIdx.x * blockDim.x + threadIdx.x;
    if (e < N_EDGES) atomicAdd(&deg[dst[e]], 1);
}

__global__ void block_sums(const int* __restrict__ deg, int* __restrict__ bsum) {
    __shared__ int s[256];
    int tid = threadIdx.x;
    int i = blockIdx.x * 256 + tid;
    int v = (i < N_NODES) ? deg[i] : 0;
    s[tid] = v;
    __syncthreads();
    #pragma unroll
    for (int off = 128; off > 0; off >>= 1) {
        if (tid < off) s[tid] += s[tid + off];
        __syncthreads();
    }
    if (tid == 0) bsum[blockIdx.x] = s[0];
}

__global__ void scan_bsums(int* __restrict__ bsum, int* __restrict__ offsets) {
    __shared__ int s[256];
    int tid = threadIdx.x;
    int v = (tid < SCAN_BLOCKS) ? bsum[tid] : 0;
    s[tid] = v;
    __syncthreads();
    for (int off = 1; off < 256; off <<= 1) {
        int t = (tid >= off) ? s[tid - off] : 0;
        __syncthreads();
        s[tid] += t;
        __syncthreads();
    }
    if (tid < SCAN_BLOCKS) bsum[tid] = s[tid] - v;   // exclusive
    if (tid == 0) offsets[N_NODES] = N_EDGES;
}

__global__ void write_offsets(const int* __restrict__ deg, const int* __restrict__ bsum,
                              int* __restrict__ offsets, float* __restrict__ deg_inv) {
    __shared__ int s[256];
    int tid = threadIdx.x;
    int i = blockIdx.x * 256 + tid;
    int v = (i < N_NODES) ? deg[i] : 0;
    s[tid] = v;
    __syncthreads();
    for (int off = 1; off < 256; off <<= 1) {
        int t = (tid >= off) ? s[tid - off] : 0;
        __syncthreads();
        s[tid] += t;
        __syncthreads();
    }
    if (i < N_NODES) {
        offsets[i] = bsum[blockIdx.x] + s[tid] - v;
        deg_inv[i] = 1.0f / (float)(v > 1 ? v : 1);
    }
}

__global__ void fill_csr(const int* __restrict__ src, const int* __restrict__ dst,
                         const int* __restrict__ offsets, int* __restrict__ cursor,
                         int* __restrict__ csr_src) {
    int e = blockIdx.x * blockDim.x + threadIdx.x;
    if (e < N_EDGES) {
        int d = dst[e];
        int p = atomicAdd(&cursor[d], 1);
        csr_src[offsets[d] + p] = src[e];
    }
}

// ---------------- mean aggregation: true-XCD dispenser, 2 nodes/wave, pair-unrolled ----------------
// Block reads its REAL XCD id; grabs half-chunks hc with (hc/2)%8 == xcd from a
// per-XCD per-layer dispenser. Writes of agg[hc] land in this XCD's L2 -> the
// gemm (same xcd class) reads them L2-warm. Gather arithmetic identical to R12.

__global__ void aggregate(const unsigned short* __restrict__ hin, const int* __restrict__ offsets,
                          const int* __restrict__ csr_src, const float* __restrict__ deg_inv,
                          unsigned short* __restrict__ agg, int* __restrict__ ctr) {
    __shared__ int sIdx;
    int tid  = threadIdx.x;
    int w    = tid >> 6;
    int lane = tid & 63;
    int nodeSel = lane >> 5;
    int l32  = lane & 31;
    int grp  = l32 >> 3;
    int p    = l32 & 7;

    int xcd = __builtin_amdgcn_s_getreg(XCC_IMM) & 7;
    int nItems = (xcd < 5) ? 782 : 780;    // half-chunks of class xcd
    int* myCtr = ctr + xcd;

    for (;;) {
        if (tid == 0) sIdx = atomicAdd(myCtr, 1);
        __syncthreads();
        int idx = sIdx;
        __syncthreads();
        if (idx >= nItems) break;
        int hc = 16 * (idx >> 1) + 2 * xcd + (idx & 1);   // (hc/2)%8 == xcd
        int node = hc * 8 + 2 * w + nodeSel;              // < 50000
        int s0 = offsets[node], e0 = offsets[node + 1];
        float di = deg_inv[node];

        float a[16];
        #pragma unroll
        for (int i = 0; i < 16; ++i) a[i] = 0.f;

        int j = s0 + grp;
        for (; j + 4 < e0; j += 8) {
            int src1 = csr_src[j];
            int src2 = csr_src[j + 4];
            const uint4* r1 = (const uint4*)(hin + (size_t)src1 * DD + p * 16);
            const uint4* r2 = (const uint4*)(hin + (size_t)src2 * DD + p * 16);
            uint4 v1a = r1[0], v1b = r1[1];
            uint4 v2a = r2[0], v2b = r2[1];
            a[0] += __uint_as_float(v1a.x << 16); a[1] += __uint_as_float(v1a.x & 0xFFFF0000u);
            a[2] += __uint_as_float(v1a.y << 16); a[3] += __uint_as_float(v1a.y & 0xFFFF0000u);
            a[4] += __uint_as_float(v1a.z << 16); a[5] += __uint_as_float(v1a.z & 0xFFFF0000u);
            a[6] += __uint_as_float(v1a.w << 16); a[7] += __uint_as_float(v1a.w & 0xFFFF0000u);
            a[8] += __uint_as_float(v1b.x << 16); a[9] += __uint_as_float(v1b.x & 0xFFFF0000u);
            a[10]+= __uint_as_float(v1b.y << 16); a[11]+= __uint_as_float(v1b.y & 0xFFFF0000u);
            a[12]+= __uint_as_float(v1b.z << 16); a[13]+= __uint_as_float(v1b.z & 0xFFFF0000u);
            a[14]+= __uint_as_float(v1b.w << 16); a[15]+= __uint_as_float(v1b.w & 0xFFFF0000u);
            a[0] += __uint_as_float(v2a.x << 16); a[1] += __uint_as_float(v2a.x & 0xFFFF0000u);
            a[2] += __uint_as_float(v2a.y << 16); a[3] += __uint_as_float(v2a.y & 0xFFFF0000u);
            a[4] += __uint_as_float(v2a.z << 16); a[5] += __uint_as_float(v2a.z & 0xFFFF0000u);
            a[6] += __uint_as_float(v2a.w << 16); a[7] += __uint_as_float(v2a.w & 0xFFFF0000u);
            a[8] += __uint_as_float(v2b.x << 16); a[9] += __uint_as_float(v2b.x & 0xFFFF0000u);
            a[10]+= __uint_as_float(v2b.y << 16); a[11]+= __uint_as_float(v2b.y & 0xFFFF0000u);
            a[12]+= __uint_as_float(v2b.z << 16); a[13]+= __uint_as_float(v2b.z & 0xFFFF0000u);
            a[14]+= __uint_as_float(v2b.w << 16); a[15]+= __uint_as_float(v2b.w & 0xFFFF0000u);
        }
        if (j < e0) {
            int src1 = csr_src[j];
            const uint4* r1 = (const uint4*)(hin + (size_t)src1 * DD + p * 16);
            uint4 v1a = r1[0], v1b = r1[1];
            a[0] += __uint_as_float(v1a.x << 16); a[1] += __uint_as_float(v1a.x & 0xFFFF0000u);
            a[2] += __uint_as_float(v1a.y << 16); a[3] += __uint_as_float(v1a.y & 0xFFFF0000u);
            a[4] += __uint_as_float(v1a.z << 16); a[5] += __uint_as_float(v1a.z & 0xFFFF0000u);
            a[6] += __uint_as_float(v1a.w << 16); a[7] += __uint_as_float(v1a.w & 0xFFFF0000u);
            a[8] += __uint_as_float(v1b.x << 16); a[9] += __uint_as_float(v1b.x & 0xFFFF0000u);
            a[10]+= __uint_as_float(v1b.y << 16); a[11]+= __uint_as_float(v1b.y & 0xFFFF0000u);
            a[12]+= __uint_as_float(v1b.z << 16); a[13]+= __uint_as_float(v1b.z & 0xFFFF0000u);
            a[14]+= __uint_as_float(v1b.w << 16); a[15]+= __uint_as_float(v1b.w & 0xFFFF0000u);
        }

        #pragma unroll
        for (int i = 0; i < 16; ++i) {
            a[i] += __shfl_xor(a[i], 8, 64);
            a[i] += __shfl_xor(a[i], 16, 64);
        }

        if (grp == 0) {
            uint4 o1, o2;
            o1.x = (unsigned)f2b(a[0] * di) | ((unsigned)f2b(a[1] * di) << 16);
            o1.y = (unsigned)f2b(a[2] * di) | ((unsigned)f2b(a[3] * di) << 16);
            o1.z = (unsigned)f2b(a[4] * di) | ((unsigned)f2b(a[5] * di) << 16);
            o1.w = (unsigned)f2b(a[6] * di) | ((unsigned)f2b(a[7] * di) << 16);
            o2.x = (unsigned)f2b(a[8] * di) | ((unsigned)f2b(a[9] * di) << 16);
            o2.y = (unsigned)f2b(a[10]* di) | ((unsigned)f2b(a[11]* di) << 16);
            o2.z = (unsigned)f2b(a[12]* di) | ((unsigned)f2b(a[13]* di) << 16);
            o2.w = (unsigned)f2b(a[14]* di) | ((unsigned)f2b(a[15]* di) << 16);
            uint4* dst = (uint4*)(agg + (size_t)node * DD + p * 16);
            dst[0] = o1;
            dst[1] = o2;
        }
    }
}

// ---------------- resident-W streaming GEMM, true-XCD dispenser ----------------
// R12 geometry (256 blocks x 512 threads, sW 64 KB + 8x8 KB sA). Each WAVE grabs
// chunks c == realXCD (mod 8) from the per-XCD dispenser -> agg/h reads L2-warm.

__launch_bounds__(512, 2)
__global__ void gemm_resW(const unsigned short* __restrict__ Agg,
                          const unsigned short* __restrict__ H,
                          const unsigned short* __restrict__ WT2,   // [128 n][256 k]
                          const float* __restrict__ bias,
                          unsigned short* __restrict__ Cout,
                          const float* __restrict__ fcW,
                          const float* __restrict__ fcb,
                          float* __restrict__ out,
                          int doFC, int* __restrict__ ctr) {
    __shared__ __align__(16) unsigned short sW[128 * 256];     // 64 KB
    __shared__ __align__(16) unsigned short sA[8][4096];       // 8 KB per wave

    int tid  = threadIdx.x;
    int wid  = tid >> 6, lane = tid & 63;
    int l15  = lane & 15, q = lane >> 4;

    for (int t = tid; t < 4096; t += 512) {
        int col = t >> 5, c = t & 31;
        uint4 v = *(const uint4*)(WT2 + (size_t)col * 256 + c * 8);
        *(uint4*)(sW + ((size_t)col * 32 + (c ^ (col & 7))) * 8) = v;
    }
    __syncthreads();

    float bcol[8];
    #pragma unroll
    for (int j = 0; j < 8; ++j) bcol[j] = bias[j * 16 + l15];

    float2 fcw[8];
    float fb0 = 0.f, fb1 = 0.f;
    if (doFC) {
        #pragma unroll
        for (int j = 0; j < 8; ++j) fcw[j] = *(const float2*)(fcW + (j * 16 + l15) * 2);
        fb0 = fcb[0]; fb1 = fcb[1];
    }

    unsigned short* myA = &sA[wid][0];
    int xcd = __builtin_amdgcn_s_getreg(XCC_IMM) & 7;
    int nItems = (xcd < 5) ? 391 : 390;     // chunks of class xcd (3125 = 8*390+5)
    int* myCtr = ctr + xcd;

    for (;;) {
        int idx;
        if (lane == 0) idx = atomicAdd(myCtr, 1);
        idx = __shfl(idx, 0, 64);
        if (idx >= nItems) break;
        int chunk = xcd + 8 * idx;
        int row0 = chunk * 16;

        #pragma unroll
        for (int i = 0; i < 4; ++i) {
            int r  = i * 4 + q;
            int cg = l15 ^ (r & 7);
            ldsdma16(Agg + (size_t)(row0 + r) * DD + cg * 8, myA + (size_t)i * 512 + lane * 8);
        }
        #pragma unroll
        for (int i = 0; i < 4; ++i) {
            int r  = i * 4 + q;
            int cg = l15 ^ (r & 7);
            ldsdma16(H + (size_t)(row0 + r) * DD + cg * 8, myA + 2048 + (size_t)i * 512 + lane * 8);
        }
        __builtin_amdgcn_s_waitcnt(0);

        floatx4 acc[8];
        #pragma unroll
        for (int j = 0; j < 8; ++j) acc[j] = (floatx4){0.f, 0.f, 0.f, 0.f};

        #pragma unroll
        for (int s = 0; s < 8; ++s) {
            int cglob = s * 4 + q;
            int reg   = cglob >> 4;
            int cin   = cglob & 15;
            bf16x8 aF = *(const bf16x8*)(myA + (size_t)reg * 2048 +
                                         ((size_t)l15 * 16 + (cin ^ (l15 & 7))) * 8);
            #pragma unroll
            for (int j = 0; j < 8; ++j) {
                int col = j * 16 + l15;
                bf16x8 bF = *(const bf16x8*)(sW + ((size_t)col * 32 + (cglob ^ (col & 7))) * 8);
                acc[j] = __builtin_amdgcn_mfma_f32_16x16x32_bf16(aF, bF, acc[j], 0, 0, 0);
            }
        }

        if (!doFC) {
            #pragma unroll
            for (int r = 0; r < 4; ++r) {
                int row = row0 + q * 4 + r;
                #pragma unroll
                for (int j = 0; j < 8; ++j) {
                    float v = acc[j][r] + bcol[j];
                    Cout[(size_t)row * DD + j * 16 + l15] = f2b(fmaxf(v, 0.f));
                }
            }
        } else {
            #pragma unroll
            for (int r = 0; r < 4; ++r) {
                float p0 = 0.f, p1 = 0.f;
                #pragma unroll
                for (int j = 0; j < 8; ++j) {
                    float v = fmaxf(acc[j][r] + bcol[j], 0.f);
                    p0 += v * fcw[j].x;
                    p1 += v * fcw[j].y;
                }
                p0 += __shfl_xor(p0, 1, 64); p1 += __shfl_xor(p1, 1, 64);
                p0 += __shfl_xor(p0, 2, 64); p1 += __shfl_xor(p1, 2, 64);
                p0 += __shfl_xor(p0, 4, 64); p1 += __shfl_xor(p1, 4, 64);
                p0 += __shfl_xor(p0, 8, 64); p1 += __shfl_xor(p1, 8, 64);
                if (l15 == 0) {
                    int row = row0 + q * 4 + r;
                    out[row * 2]     = p0 + fb0;
                    out[row * 2 + 1] = p1 + fb1;
                }
            }
        }
    }
}

// ---------------- launch ----------------

extern "C" void kernel_launch(void* const* d_in, const int* in_sizes, int n_in,
                              void* d_out, int out_size, void* d_ws, size_t ws_size,
                              hipStream_t stream) {
    const float* x    = (const float*)d_in[0];
    const int*   ei   = (const int*)d_in[1];
    const float* Wl   = (const float*)d_in[2];
    const float* Wr   = (const float*)d_in[3];
    const float* bl   = (const float*)d_in[4];
    const float* fcW  = (const float*)d_in[5];
    const float* fcb  = (const float*)d_in[6];
    float* out = (float*)d_out;

    const int* srcIdx = ei;
    const int* dstIdx = ei + N_EDGES;

    char* ws = (char*)d_ws;
    size_t off = 0;
    auto bump = [&](size_t bytes) { char* p = ws + off; off = (off + bytes + 255) & ~(size_t)255; return p; };
    int*   deg     = (int*)  bump(N_NODES * 4);
    int*   cursor  = (int*)  bump(N_NODES * 4);
    int*   offsets = (int*)  bump((N_NODES + 1) * 4);
    int*   bsum    = (int*)  bump(SCAN_BLOCKS * 4);
    float* deg_inv = (float*)bump(N_NODES * 4);
    int*   csr     = (int*)  bump(N_EDGES * 4);
    int*   disp    = (int*)  bump(112 * 4);   // [6 layers][8 xcd] agg + [6][8] gemm
    unsigned short* hx   = (unsigned short*)bump((size_t)N_NODES * DD * 2);
    unsigned short* hb0  = (unsigned short*)bump((size_t)N_NODES * DD * 2);
    unsigned short* hb1  = (unsigned short*)bump((size_t)N_NODES * DD * 2);
    unsigned short* agg  = (unsigned short*)bump((size_t)N_NODES * DD * 2);
    unsigned short* WT2  = (unsigned short*)bump((size_t)N_LAYERS * 128 * 256 * 2);
    (void)ws_size;

    prep_all<<<(PREP_TOTAL + 255) / 256, 256, 0, stream>>>(x, hx, Wl, Wr, WT2, deg, cursor, disp);
    count_deg<<<(N_EDGES + 255) / 256, 256, 0, stream>>>(dstIdx, deg);
    block_sums<<<SCAN_BLOCKS, 256, 0, stream>>>(deg, bsum);
    scan_bsums<<<1, 256, 0, stream>>>(bsum, offsets);
    write_offsets<<<SCAN_BLOCKS, 256, 0, stream>>>(deg, bsum, offsets, deg_inv);
    fill_csr<<<(N_EDGES + 255) / 256, 256, 0, stream>>>(srcIdx, dstIdx, offsets, cursor, csr);

    const unsigned short* hin = hx;
    unsigned short* hbuf[2] = { hb0, hb1 };
    for (int l = 0; l < N_LAYERS; ++l) {
        int last = (l == N_LAYERS - 1);
        aggregate<<<AGG_BLOCKS, 256, 0, stream>>>(hin, offsets, csr, deg_inv, agg,
                                                  disp + l * 8);
        unsigned short* hout = hbuf[l & 1];
        gemm_resW<<<256, 512, 0, stream>>>(
            agg, hin, WT2 + (size_t)l * 128 * 256, bl + (size_t)l * DD, hout,
            fcW, fcb, out, last, disp + 48 + l * 8);
        hin = hout;
    }
}

// Round 16
// 341.843 us; speedup vs baseline: 4.1611x; 4.1611x over previous
//
#include <hip/hip_runtime.h>
#include <hip/hip_bf16.h>

#define N_NODES 50000
#define N_EDGES 600000
#define DD 128
#define N_LAYERS 6
#define SCAN_BLOCKS 196   // ceil(50000/256)
#define N_CHUNKS 3125     // 50000 / 16 exactly
#define AGG_BLOCKS 6256

#define XB16_T 1600000
#define ZERO_T 50000
#define PREPW_T 196608
#define PREP_TOTAL (XB16_T + ZERO_T + PREPW_T)

typedef __attribute__((ext_vector_type(8))) short bf16x8;
typedef __attribute__((ext_vector_type(4))) float floatx4;

__device__ __forceinline__ unsigned short f2b(float f) {
    unsigned u = __float_as_uint(f);
    unsigned r = (u + 0x7FFFu + ((u >> 16) & 1u)) >> 16;
    return (unsigned short)r;
}

// ---------------- merged prep ----------------

__global__ void prep_all(const float* __restrict__ x, unsigned short* __restrict__ hx,
                         const float* __restrict__ Wl, const float* __restrict__ Wr,
                         unsigned short* __restrict__ WT2,
                         int* __restrict__ deg, int* __restrict__ cursor) {
    int gid = blockIdx.x * blockDim.x + threadIdx.x;
    if (gid < XB16_T) {
        int b = gid * 4;
        float4 v = *(const float4*)(x + b);
        ushort4 o;
        o.x = f2b(v.x); o.y = f2b(v.y); o.z = f2b(v.z); o.w = f2b(v.w);
        *(ushort4*)(hx + b) = o;
    } else if (gid < XB16_T + ZERO_T) {
        int i = gid - XB16_T;
        deg[i] = 0; cursor[i] = 0;
    } else if (gid < PREP_TOTAL) {
        int idx = gid - (XB16_T + ZERO_T);
        int l   = idx >> 15;
        int rem = idx & 32767;
        int n   = rem >> 8;
        int k2  = rem & 255;
        const float* W = (k2 < 128 ? Wl : Wr) + (size_t)l * DD * DD + (size_t)(k2 & 127) * DD + n;
        WT2[idx] = f2b(*W);
    }
}

// ---------------- CSR build ----------------

__global__ void count_deg(const int* __restrict__ dst, int* __restrict__ deg) {
    int e = blockIdx.x * blockDim.x + threadIdx.x;
    if (e < N_EDGES) atomicAdd(&deg[dst[e]], 1);
}

__global__ void block_sums(const int* __restrict__ deg, int* __restrict__ bsum) {
    __shared__ int s[256];
    int tid = threadIdx.x;
    int i = blockIdx.x * 256 + tid;
    int v = (i < N_NODES) ? deg[i] : 0;
    s[tid] = v;
    __syncthreads();
    #pragma unroll
    for (int off = 128; off > 0; off >>= 1) {
        if (tid < off) s[tid] += s[tid + off];
        __syncthreads();
    }
    if (tid == 0) bsum[blockIdx.x] = s[0];
}

__global__ void scan_bsums(int* __restrict__ bsum, int* __restrict__ offsets) {
    __shared__ int s[256];
    int tid = threadIdx.x;
    int v = (tid < SCAN_BLOCKS) ? bsum[tid] : 0;
    s[tid] = v;
    __syncthreads();
    for (int off = 1; off < 256; off <<= 1) {
        int t = (tid >= off) ? s[tid - off] : 0;
        __syncthreads();
        s[tid] += t;
        __syncthreads();
    }
    if (tid < SCAN_BLOCKS) bsum[tid] = s[tid] - v;   // exclusive
    if (tid == 0) offsets[N_NODES] = N_EDGES;
}

__global__ void write_offsets(const int* __restrict__ deg, const int* __restrict__ bsum,
                              int* __restrict__ offsets, float* __restrict__ deg_inv) {
    __shared__ int s[256];
    int tid = threadIdx.x;
    int i = blockIdx.x * 256 + tid;
    int v = (i < N_NODES) ? deg[i] : 0;
    s[tid] = v;
    __syncthreads();
    for (int off = 1; off < 256; off <<= 1) {
        int t = (tid >= off) ? s[tid - off] : 0;
        __syncthreads();
        s[tid] += t;
        __syncthreads();
    }
    if (i < N_NODES) {
        offsets[i] = bsum[blockIdx.x] + s[tid] - v;
        deg_inv[i] = 1.0f / (float)(v > 1 ? v : 1);
    }
}

__global__ void fill_csr(const int* __restrict__ src, const int* __restrict__ dst,
                         const int* __restrict__ offsets, int* __restrict__ cursor,
                         int* __restrict__ csr_src) {
    int e = blockIdx.x * blockDim.x + threadIdx.x;
    if (e < N_EDGES) {
        int d = dst[e];
        int p = atomicAdd(&cursor[d], 1);
        csr_src[offsets[d] + p] = src[e];
    }
}

// ---------------- mean aggregation: R12-exact (best measured) ----------------

__global__ void aggregate(const unsigned short* __restrict__ hin, const int* __restrict__ offsets,
                          const int* __restrict__ csr_src, const float* __restrict__ deg_inv,
                          unsigned short* __restrict__ agg) {
    int w    = threadIdx.x >> 6;
    int lane = threadIdx.x & 63;
    int nodeSel = lane >> 5;
    int l32  = lane & 31;
    int grp  = l32 >> 3;
    int p    = l32 & 7;

    int b = blockIdx.x;
    int x = b & 7, s = b >> 3;
    int hc = 16 * (s >> 1) + 2 * x + (s & 1);
    int node = hc * 8 + 2 * w + nodeSel;
    if (node >= N_NODES) return;
    int s0 = offsets[node], e0 = offsets[node + 1];
    float di = deg_inv[node];

    float a[16];
    #pragma unroll
    for (int i = 0; i < 16; ++i) a[i] = 0.f;

    const unsigned short* base = hin;
    int j = s0 + grp;
    for (; j + 4 < e0; j += 8) {
        int src1 = csr_src[j];
        int src2 = csr_src[j + 4];
        const uint4* r1 = (const uint4*)(base + (size_t)src1 * DD + p * 16);
        const uint4* r2 = (const uint4*)(base + (size_t)src2 * DD + p * 16);
        uint4 v1a = r1[0], v1b = r1[1];
        uint4 v2a = r2[0], v2b = r2[1];
        a[0] += __uint_as_float(v1a.x << 16); a[1] += __uint_as_float(v1a.x & 0xFFFF0000u);
        a[2] += __uint_as_float(v1a.y << 16); a[3] += __uint_as_float(v1a.y & 0xFFFF0000u);
        a[4] += __uint_as_float(v1a.z << 16); a[5] += __uint_as_float(v1a.z & 0xFFFF0000u);
        a[6] += __uint_as_float(v1a.w << 16); a[7] += __uint_as_float(v1a.w & 0xFFFF0000u);
        a[8] += __uint_as_float(v1b.x << 16); a[9] += __uint_as_float(v1b.x & 0xFFFF0000u);
        a[10]+= __uint_as_float(v1b.y << 16); a[11]+= __uint_as_float(v1b.y & 0xFFFF0000u);
        a[12]+= __uint_as_float(v1b.z << 16); a[13]+= __uint_as_float(v1b.z & 0xFFFF0000u);
        a[14]+= __uint_as_float(v1b.w << 16); a[15]+= __uint_as_float(v1b.w & 0xFFFF0000u);
        a[0] += __uint_as_float(v2a.x << 16); a[1] += __uint_as_float(v2a.x & 0xFFFF0000u);
        a[2] += __uint_as_float(v2a.y << 16); a[3] += __uint_as_float(v2a.y & 0xFFFF0000u);
        a[4] += __uint_as_float(v2a.z << 16); a[5] += __uint_as_float(v2a.z & 0xFFFF0000u);
        a[6] += __uint_as_float(v2a.w << 16); a[7] += __uint_as_float(v2a.w & 0xFFFF0000u);
        a[8] += __uint_as_float(v2b.x << 16); a[9] += __uint_as_float(v2b.x & 0xFFFF0000u);
        a[10]+= __uint_as_float(v2b.y << 16); a[11]+= __uint_as_float(v2b.y & 0xFFFF0000u);
        a[12]+= __uint_as_float(v2b.z << 16); a[13]+= __uint_as_float(v2b.z & 0xFFFF0000u);
        a[14]+= __uint_as_float(v2b.w << 16); a[15]+= __uint_as_float(v2b.w & 0xFFFF0000u);
    }
    if (j < e0) {
        int src1 = csr_src[j];
        const uint4* r1 = (const uint4*)(base + (size_t)src1 * DD + p * 16);
        uint4 v1a = r1[0], v1b = r1[1];
        a[0] += __uint_as_float(v1a.x << 16); a[1] += __uint_as_float(v1a.x & 0xFFFF0000u);
        a[2] += __uint_as_float(v1a.y << 16); a[3] += __uint_as_float(v1a.y & 0xFFFF0000u);
        a[4] += __uint_as_float(v1a.z << 16); a[5] += __uint_as_float(v1a.z & 0xFFFF0000u);
        a[6] += __uint_as_float(v1a.w << 16); a[7] += __uint_as_float(v1a.w & 0xFFFF0000u);
        a[8] += __uint_as_float(v1b.x << 16); a[9] += __uint_as_float(v1b.x & 0xFFFF0000u);
        a[10]+= __uint_as_float(v1b.y << 16); a[11]+= __uint_as_float(v1b.y & 0xFFFF0000u);
        a[12]+= __uint_as_float(v1b.z << 16); a[13]+= __uint_as_float(v1b.z & 0xFFFF0000u);
        a[14]+= __uint_as_float(v1b.w << 16); a[15]+= __uint_as_float(v1b.w & 0xFFFF0000u);
    }

    #pragma unroll
    for (int i = 0; i < 16; ++i) {
        a[i] += __shfl_xor(a[i], 8, 64);
        a[i] += __shfl_xor(a[i], 16, 64);
    }

    if (grp == 0) {
        uint4 o1, o2;
        o1.x = (unsigned)f2b(a[0] * di) | ((unsigned)f2b(a[1] * di) << 16);
        o1.y = (unsigned)f2b(a[2] * di) | ((unsigned)f2b(a[3] * di) << 16);
        o1.z = (unsigned)f2b(a[4] * di) | ((unsigned)f2b(a[5] * di) << 16);
        o1.w = (unsigned)f2b(a[6] * di) | ((unsigned)f2b(a[7] * di) << 16);
        o2.x = (unsigned)f2b(a[8] * di) | ((unsigned)f2b(a[9] * di) << 16);
        o2.y = (unsigned)f2b(a[10]* di) | ((unsigned)f2b(a[11]* di) << 16);
        o2.z = (unsigned)f2b(a[12]* di) | ((unsigned)f2b(a[13]* di) << 16);
        o2.w = (unsigned)f2b(a[14]* di) | ((unsigned)f2b(a[15]* di) << 16);
        uint4* dst = (uint4*)(agg + (size_t)node * DD + p * 16);
        dst[0] = o1;
        dst[1] = o2;
    }
}

// ---------------- GEMM: W in LDS, A DIRECT from global (no sA, no drain) ----------------
// 512 blocks x 512 threads, LDS = sW only (64 KB) -> 2 blocks/CU, 4 waves/SIMD.
// Each wave handles exactly one 16-row chunk (4096 waves >= 3125). A-fragments:
// lane (l15,q) reads row row0+l15, k-chunk s*4+q directly (8 independent 16-B
// loads; compiler interleaves MFMAs with fine-grained vmcnt). B from swizzled sW.
// MFMA order identical to R12 -> bitwise-identical output.

__launch_bounds__(512, 4)
__global__ void gemm_resW(const unsigned short* __restrict__ Agg,
                          const unsigned short* __restrict__ H,
                          const unsigned short* __restrict__ WT2,   // [128 n][256 k]
                          const float* __restrict__ bias,
                          unsigned short* __restrict__ Cout,
                          const float* __restrict__ fcW,
                          const float* __restrict__ fcb,
                          float* __restrict__ out,
                          int doFC) {
    __shared__ __align__(16) unsigned short sW[128 * 256];     // 64 KB

    int tid  = threadIdx.x;
    int wid  = tid >> 6, lane = tid & 63;
    int l15  = lane & 15, q = lane >> 4;

    // ---- fill sW (swizzled: chunk c of col stored at col*32 + (c ^ (col&7))) ----
    for (int t = tid; t < 4096; t += 512) {
        int col = t >> 5, c = t & 31;
        uint4 v = *(const uint4*)(WT2 + (size_t)col * 256 + c * 8);
        *(uint4*)(sW + ((size_t)col * 32 + (c ^ (col & 7))) * 8) = v;
    }
    __syncthreads();

    int chunk = blockIdx.x * 8 + wid;
    if (chunk >= N_CHUNKS) return;
    int row0 = chunk * 16;

    float bcol[8];
    #pragma unroll
    for (int j = 0; j < 8; ++j) bcol[j] = bias[j * 16 + l15];

    // ---- A-fragments direct from global: 8 independent 16-B loads ----
    const unsigned short* Arow = Agg + (size_t)(row0 + l15) * DD;
    const unsigned short* Hrow = H   + (size_t)(row0 + l15) * DD;
    bf16x8 aF[8];
    #pragma unroll
    for (int s = 0; s < 4; ++s)
        aF[s] = *(const bf16x8*)(Arow + (s * 4 + q) * 8);
    #pragma unroll
    for (int s = 4; s < 8; ++s)
        aF[s] = *(const bf16x8*)(Hrow + (s * 4 + q - 16) * 8);

    floatx4 acc[8];
    #pragma unroll
    for (int j = 0; j < 8; ++j) acc[j] = (floatx4){0.f, 0.f, 0.f, 0.f};

    #pragma unroll
    for (int s = 0; s < 8; ++s) {
        int cglob = s * 4 + q;
        #pragma unroll
        for (int j = 0; j < 8; ++j) {
            int col = j * 16 + l15;
            bf16x8 bF = *(const bf16x8*)(sW + ((size_t)col * 32 + (cglob ^ (col & 7))) * 8);
            acc[j] = __builtin_amdgcn_mfma_f32_16x16x32_bf16(aF[s], bF, acc[j], 0, 0, 0);
        }
    }

    if (!doFC) {
        #pragma unroll
        for (int r = 0; r < 4; ++r) {
            int row = row0 + q * 4 + r;
            #pragma unroll
            for (int j = 0; j < 8; ++j) {
                float v = acc[j][r] + bcol[j];
                Cout[(size_t)row * DD + j * 16 + l15] = f2b(fmaxf(v, 0.f));
            }
        }
    } else {
        float2 fcw[8];
        #pragma unroll
        for (int j = 0; j < 8; ++j) fcw[j] = *(const float2*)(fcW + (j * 16 + l15) * 2);
        float fb0 = fcb[0], fb1 = fcb[1];
        #pragma unroll
        for (int r = 0; r < 4; ++r) {
            float p0 = 0.f, p1 = 0.f;
            #pragma unroll
            for (int j = 0; j < 8; ++j) {
                float v = fmaxf(acc[j][r] + bcol[j], 0.f);
                p0 += v * fcw[j].x;
                p1 += v * fcw[j].y;
            }
            p0 += __shfl_xor(p0, 1, 64); p1 += __shfl_xor(p1, 1, 64);
            p0 += __shfl_xor(p0, 2, 64); p1 += __shfl_xor(p1, 2, 64);
            p0 += __shfl_xor(p0, 4, 64); p1 += __shfl_xor(p1, 4, 64);
            p0 += __shfl_xor(p0, 8, 64); p1 += __shfl_xor(p1, 8, 64);
            if (l15 == 0) {
                int row = row0 + q * 4 + r;
                out[row * 2]     = p0 + fb0;
                out[row * 2 + 1] = p1 + fb1;
            }
        }
    }
}

// ---------------- launch ----------------

extern "C" void kernel_launch(void* const* d_in, const int* in_sizes, int n_in,
                              void* d_out, int out_size, void* d_ws, size_t ws_size,
                              hipStream_t stream) {
    const float* x    = (const float*)d_in[0];
    const int*   ei   = (const int*)d_in[1];
    const float* Wl   = (const float*)d_in[2];
    const float* Wr   = (const float*)d_in[3];
    const float* bl   = (const float*)d_in[4];
    const float* fcW  = (const float*)d_in[5];
    const float* fcb  = (const float*)d_in[6];
    float* out = (float*)d_out;

    const int* srcIdx = ei;
    const int* dstIdx = ei + N_EDGES;

    char* ws = (char*)d_ws;
    size_t off = 0;
    auto bump = [&](size_t bytes) { char* p = ws + off; off = (off + bytes + 255) & ~(size_t)255; return p; };
    int*   deg     = (int*)  bump(N_NODES * 4);
    int*   cursor  = (int*)  bump(N_NODES * 4);
    int*   offsets = (int*)  bump((N_NODES + 1) * 4);
    int*   bsum    = (int*)  bump(SCAN_BLOCKS * 4);
    float* deg_inv = (float*)bump(N_NODES * 4);
    int*   csr     = (int*)  bump(N_EDGES * 4);
    unsigned short* hx   = (unsigned short*)bump((size_t)N_NODES * DD * 2);
    unsigned short* hb0  = (unsigned short*)bump((size_t)N_NODES * DD * 2);
    unsigned short* hb1  = (unsigned short*)bump((size_t)N_NODES * DD * 2);
    unsigned short* agg  = (unsigned short*)bump((size_t)N_NODES * DD * 2);
    unsigned short* WT2  = (unsigned short*)bump((size_t)N_LAYERS * 128 * 256 * 2);
    (void)ws_size;

    prep_all<<<(PREP_TOTAL + 255) / 256, 256, 0, stream>>>(x, hx, Wl, Wr, WT2, deg, cursor);
    count_deg<<<(N_EDGES + 255) / 256, 256, 0, stream>>>(dstIdx, deg);
    block_sums<<<SCAN_BLOCKS, 256, 0, stream>>>(deg, bsum);
    scan_bsums<<<1, 256, 0, stream>>>(bsum, offsets);
    write_offsets<<<SCAN_BLOCKS, 256, 0, stream>>>(deg, bsum, offsets, deg_inv);
    fill_csr<<<(N_EDGES + 255) / 256, 256, 0, stream>>>(srcIdx, dstIdx, offsets, cursor, csr);

    const unsigned short* hin = hx;
    unsigned short* hbuf[2] = { hb0, hb1 };
    for (int l = 0; l < N_LAYERS; ++l) {
        int last = (l == N_LAYERS - 1);
        aggregate<<<AGG_BLOCKS, 256, 0, stream>>>(hin, offsets, csr, deg_inv, agg);
        unsigned short* hout = hbuf[l & 1];
        gemm_resW<<<(N_CHUNKS + 7) / 8, 512, 0, stream>>>(
            agg, hin, WT2 + (size_t)l * 128 * 256, bl + (size_t)l * DD, hout,
            fcW, fcb, out, last);
        hin = hout;
    }
}